// Round 8
// baseline (169.314 us; speedup 1.0000x reference)
//
#include <hip/hip_runtime.h>

// FlexAttention (sliding-window causal + per-head sink), R17.
// B=2,H=16,S=2048,D=64,W=1024.
//
// R17 = R16 compute core with 64 q PER WAVE (NT=128, 2 waves/block).
// Evidence R9..R16: main pinned at ~44us across huge changes in staging,
// conflicts, HBM, occupancy -> per-wave serial chain x wave-tile count is
// the invariant; the never-varied knob is work/wave. Doubling q/wave:
//  - K/V LDS reads (16 x b128) now serve 64 q: per-q LDS traffic HALVED.
//  - K/V A-frags reused for both q-halves; 32 MFMA as 4 indep chains.
//  - fixed per-tile costs (tree-max/xmax/defer/staging addr) amortized 2x.
//  - staging loads issued AFTER exchange (hidden under PV, short live
//    range) so peak live ~220 < 256 cap of __launch_bounds__(128,2).
//  - exp2-domain softmax: log2e folded into Q scale + sink; exps are one
//    v_exp_f32 each (no mul). COMBINE USES exp2f TOO (m is log2-domain).
// Keeps: XCD-pinned decode, defer-max(THR 11 in log2) + tree-max,
// permlane32 exchange + xmax32/xsum32 (R16-proven), s_setprio, 24-bin
// schedule, LDS 32KB dbuf, one barrier/tile, WS layout (26.7MB proven).
// Layouts (m74/m101): A[m=l&31][k=(l>>5)*8+j], B[k=..][n=l&31],
// C/D[row=(rg&3)+8*(rg>>2)+4*(l>>5)][col=l&31].

typedef __bf16 bf16x8 __attribute__((ext_vector_type(8)));
typedef __bf16 bf16x4 __attribute__((ext_vector_type(4)));
typedef float  f32x16 __attribute__((ext_vector_type(16)));

#define NT 128
#define NEG_BIG (-3.0e38f)
#define LOG2E 1.44269504088896f

__device__ __forceinline__ int swz(int row, int gran) {
    return row * 64 + ((gran ^ ((row >> 1) & 7)) << 3);
}

// v_permlane32_swap_b32 a, b:  a' = {a[0:31], b[0:31]}, b' = {a[32:63], b[32:63]}
__device__ __forceinline__ void plswap(unsigned &a, unsigned &b) {
    asm("v_permlane32_swap_b32 %0, %1" : "+v"(a), "+v"(b));
}

__device__ __forceinline__ float xmax32(float x) {
    float a = x, b;
    asm("v_mov_b32 %0, %1" : "=&v"(b) : "v"(a));
    asm("v_permlane32_swap_b32 %0, %1" : "+v"(a), "+v"(b));
    return fmaxf(a, b);
}

__device__ __forceinline__ float xsum32(float x) {
    float a = x, b;
    asm("v_mov_b32 %0, %1" : "=&v"(b) : "v"(a));
    asm("v_permlane32_swap_b32 %0, %1" : "+v"(a), "+v"(b));
    return a + b;
}

// P -> B-frag exchange (R16-proven): sa = keys 0-31 rows, sb = keys 32-63.
__device__ __forceinline__ void exch_bp(const f32x16& sa, const f32x16& sb,
                                        bf16x8 bp[4]) {
    union B4U { bf16x4 v; unsigned u[2]; };
    B4U a0, b0, a1, b1, a2, b2, a3, b3;
    a0.v = bf16x4{ (__bf16)sa[0],  (__bf16)sa[1],  (__bf16)sa[2],  (__bf16)sa[3]  };
    b0.v = bf16x4{ (__bf16)sa[4],  (__bf16)sa[5],  (__bf16)sa[6],  (__bf16)sa[7]  };
    a1.v = bf16x4{ (__bf16)sa[8],  (__bf16)sa[9],  (__bf16)sa[10], (__bf16)sa[11] };
    b1.v = bf16x4{ (__bf16)sa[12], (__bf16)sa[13], (__bf16)sa[14], (__bf16)sa[15] };
    a2.v = bf16x4{ (__bf16)sb[0],  (__bf16)sb[1],  (__bf16)sb[2],  (__bf16)sb[3]  };
    b2.v = bf16x4{ (__bf16)sb[4],  (__bf16)sb[5],  (__bf16)sb[6],  (__bf16)sb[7]  };
    a3.v = bf16x4{ (__bf16)sb[8],  (__bf16)sb[9],  (__bf16)sb[10], (__bf16)sb[11] };
    b3.v = bf16x4{ (__bf16)sb[12], (__bf16)sb[13], (__bf16)sb[14], (__bf16)sb[15] };
    plswap(a0.u[0], b0.u[0]); plswap(a0.u[1], b0.u[1]);
    plswap(a1.u[0], b1.u[0]); plswap(a1.u[1], b1.u[1]);
    plswap(a2.u[0], b2.u[0]); plswap(a2.u[1], b2.u[1]);
    plswap(a3.u[0], b3.u[0]); plswap(a3.u[1], b3.u[1]);
    #pragma unroll
    for (int e = 0; e < 4; ++e) {
        bp[0][e] = a0.v[e]; bp[0][4+e] = b0.v[e];
        bp[1][e] = a1.v[e]; bp[1][4+e] = b1.v[e];
        bp[2][e] = a2.v[e]; bp[2][4+e] = b2.v[e];
        bp[3][e] = a3.v[e]; bp[3][4+e] = b3.v[e];
    }
}

__device__ __forceinline__ void mask_half(f32x16& s0, f32x16& s1,
                                          int k0, int qi, int W, int hl) {
    #pragma unroll
    for (int rg = 0; rg < 16; ++rg) {
        const int kb2 = (rg & 3) + 8 * (rg >> 2) + 4 * hl;
        const int ki0 = k0 + kb2, ki1 = k0 + 32 + kb2;
        if (!((ki0 <= qi) && (qi - ki0 <= W))) s0[rg] = -1e30f;
        if (!((ki1 <= qi) && (qi - ki1 <= W))) s1[rg] = -1e30f;
    }
}

__device__ __forceinline__ float tree_max(const f32x16& s0, const f32x16& s1) {
    float q4[8];
    #pragma unroll
    for (int i = 0; i < 4; ++i) {
        q4[i]   = fmaxf(fmaxf(s0[4*i], s0[4*i+1]), fmaxf(s0[4*i+2], s0[4*i+3]));
        q4[4+i] = fmaxf(fmaxf(s1[4*i], s1[4*i+1]), fmaxf(s1[4*i+2], s1[4*i+3]));
    }
    return fmaxf(fmaxf(fmaxf(q4[0], q4[1]), fmaxf(q4[2], q4[3])),
                 fmaxf(fmaxf(q4[4], q4[5]), fmaxf(q4[6], q4[7])));
}

// ---- baked schedule (R5/R6, verified): 24 bins/bh x exactly 9 tiles ----
__device__ const int SEG_N[24] = {3,2,2,2,2,1,2,1, 1,1,1,1,1,1,1,1, 1,1,1,1,1,1,1,1};
__device__ const int SEG_IT[24][3] = {
  {0,1,2},{2,3,0},{3,4,0},{4,5,0},{5,6,0},{6,0,0},{6,7,0},{7,0,0},
  {8,0,0},{8,0,0},{9,0,0},{9,0,0},{10,0,0},{10,0,0},{11,0,0},{11,0,0},
  {12,0,0},{12,0,0},{13,0,0},{13,0,0},{14,0,0},{14,0,0},{15,0,0},{15,0,0}};
__device__ const int SEG_J0[24][3] = {
  {0,0,0},{3,0,0},{6,0,0},{7,0,0},{6,0,0},{3,0,0},{12,0,0},{7,0,0},
  {0,0,0},{9,0,0},{0,0,0},{9,0,0},{0,0,0},{9,0,0},{0,0,0},{9,0,0},
  {0,0,0},{9,0,0},{0,0,0},{9,0,0},{0,0,0},{9,0,0},{0,0,0},{9,0,0}};
__device__ const int SEG_J1[24][3] = {
  {2,4,3},{6,6,0},{8,7,0},{10,6,0},{12,3,0},{12,0,0},{14,7,0},{16,0,0},
  {9,0,0},{18,0,0},{9,0,0},{18,0,0},{9,0,0},{18,0,0},{9,0,0},{18,0,0},
  {9,0,0},{18,0,0},{9,0,0},{18,0,0},{9,0,0},{18,0,0},{9,0,0},{18,0,0}};
__device__ const int SEG_SX[24][3] = {
  {0,0,0},{1,0,0},{1,0,0},{1,0,0},{1,0,0},{1,0,0},{2,0,0},{1,0,0},
  {0,0,0},{1,0,0},{0,0,0},{1,0,0},{0,0,0},{1,0,0},{0,0,0},{1,0,0},
  {0,0,0},{1,0,0},{0,0,0},{1,0,0},{0,0,0},{1,0,0},{0,0,0},{1,0,0}};
__device__ const int NSEG_ITEM[16] = {1,1,2,2,2,2,3,2, 2,2,2,2,2,2,2,2};

__global__ __launch_bounds__(NT, 2) void flex_r17_main(
    const float* __restrict__ Q, const float* __restrict__ K,
    const float* __restrict__ V, const float* __restrict__ SINKW,
    const int* __restrict__ SWIN, void* __restrict__ WS,
    float* __restrict__ OUT, const int H, const int S)
{
    const int t    = threadIdx.x;
    const int lane = t & 63;
    const int w    = t >> 6;          // 0..1 : wave owns q [64w, 64w+64)
    const int c    = lane & 31;
    const int hl   = lane >> 5;
    const int W    = SWIN[0];
    const float scale = 0.125f * LOG2E;   // exp2 domain

    const int NBH = gridDim.x / 24;
    int bh, b24;
    if ((NBH & 7) == 0) {
        const int xcd  = blockIdx.x & 7;
        const int rest = blockIdx.x >> 3;
        const int G    = NBH >> 3;
        bh  = (rest % G) * 8 + xcd;
        b24 = rest / G;
    } else {
        bh  = blockIdx.x / 24;
        b24 = blockIdx.x - bh * 24;
    }
    const int h   = bh % H;
    const float sw = SINKW[h] * LOG2E;    // sink logit in log2 domain

    __shared__ __align__(16) __bf16 k_lds[2][64 * 64];
    __shared__ __align__(16) __bf16 v_lds[2][64 * 64];

    const size_t basebh = (size_t)bh * S * 64;
    const float4* kp4 = (const float4*)(K + basebh);
    const float4* vp4 = (const float4*)(V + basebh);
    __bf16* O_ws  = (__bf16*)WS;
    float2* ml_ws = (float2*)((char*)WS + (size_t)NBH * 48 * 16384);

    const int dgi = t & 15;   // V staging: dims 4dgi..+3
    const int kg  = t >> 4;   // V staging: keys 8kg..+7  (0..7)
    float4 kreg[8], vreg[8];

    const int ns = SEG_N[b24];

    // ---- prologue: load + stage first tile into buffer 0 ----
    {
        const int it0 = SEG_IT[b24][0];
        const int ktA0 = (2 * it0 - 16 > 0) ? (2 * it0 - 16) : 0;
        const int kt = ktA0 + SEG_J0[b24][0];
        #pragma unroll
        for (int i = 0; i < 8; ++i) kreg[i] = kp4[kt * 1024 + i * NT + t];
        #pragma unroll
        for (int kk = 0; kk < 8; ++kk) vreg[kk] = vp4[kt * 1024 + (8 * kg + kk) * 16 + dgi];
        #pragma unroll
        for (int i = 0; i < 8; ++i) {
            const int flat = i * NT + t;
            const int key = flat >> 4, dd = flat & 15;
            float4 f = kreg[i];
            bf16x4 b = { (__bf16)f.x, (__bf16)f.y, (__bf16)f.z, (__bf16)f.w };
            *(bf16x4*)&k_lds[0][swz(key, dd >> 1) + (dd & 1) * 4] = b;
        }
        {
            bf16x4 p0, p1;
            p0 = bf16x4{ (__bf16)vreg[0].x, (__bf16)vreg[1].x, (__bf16)vreg[2].x, (__bf16)vreg[3].x };
            p1 = bf16x4{ (__bf16)vreg[4].x, (__bf16)vreg[5].x, (__bf16)vreg[6].x, (__bf16)vreg[7].x };
            *(bf16x4*)&v_lds[0][swz(4 * dgi + 0, kg) + 0] = p0;
            *(bf16x4*)&v_lds[0][swz(4 * dgi + 0, kg) + 4] = p1;
            p0 = bf16x4{ (__bf16)vreg[0].y, (__bf16)vreg[1].y, (__bf16)vreg[2].y, (__bf16)vreg[3].y };
            p1 = bf16x4{ (__bf16)vreg[4].y, (__bf16)vreg[5].y, (__bf16)vreg[6].y, (__bf16)vreg[7].y };
            *(bf16x4*)&v_lds[0][swz(4 * dgi + 1, kg) + 0] = p0;
            *(bf16x4*)&v_lds[0][swz(4 * dgi + 1, kg) + 4] = p1;
            p0 = bf16x4{ (__bf16)vreg[0].z, (__bf16)vreg[1].z, (__bf16)vreg[2].z, (__bf16)vreg[3].z };
            p1 = bf16x4{ (__bf16)vreg[4].z, (__bf16)vreg[5].z, (__bf16)vreg[6].z, (__bf16)vreg[7].z };
            *(bf16x4*)&v_lds[0][swz(4 * dgi + 2, kg) + 0] = p0;
            *(bf16x4*)&v_lds[0][swz(4 * dgi + 2, kg) + 4] = p1;
            p0 = bf16x4{ (__bf16)vreg[0].w, (__bf16)vreg[1].w, (__bf16)vreg[2].w, (__bf16)vreg[3].w };
            p1 = bf16x4{ (__bf16)vreg[4].w, (__bf16)vreg[5].w, (__bf16)vreg[6].w, (__bf16)vreg[7].w };
            *(bf16x4*)&v_lds[0][swz(4 * dgi + 3, kg) + 0] = p0;
            *(bf16x4*)&v_lds[0][swz(4 * dgi + 3, kg) + 4] = p1;
        }
    }

    int par = 0;

    for (int s = 0; s < ns; ++s) {
        const int item = SEG_IT[b24][s];
        const int j0   = SEG_J0[b24][s];
        const int j1   = SEG_J1[b24][s];
        const int sidx = SEG_SX[b24][s];
        const int ktA  = (2 * item - 16 > 0) ? (2 * item - 16) : 0;
        const int qw0  = item * 128 + 64 * w;
        const int qi0  = qw0 + c;         // q-half 0
        const int qi1  = qw0 + 32 + c;    // q-half 1

        // ---- Q B-fragments for BOTH halves (pre-scaled, log2 domain) ----
        bf16x8 bq0[4], bq1[4];
        {
            const float4* qpa = (const float4*)(Q + basebh + (size_t)qi0 * 64);
            const float4* qpb = (const float4*)(Q + basebh + (size_t)qi1 * 64);
            #pragma unroll
            for (int ks = 0; ks < 4; ++ks) {
                float4 f0 = qpa[4 * ks + 2 * hl];
                float4 f1 = qpa[4 * ks + 2 * hl + 1];
                bq0[ks][0] = (__bf16)(f0.x * scale); bq0[ks][1] = (__bf16)(f0.y * scale);
                bq0[ks][2] = (__bf16)(f0.z * scale); bq0[ks][3] = (__bf16)(f0.w * scale);
                bq0[ks][4] = (__bf16)(f1.x * scale); bq0[ks][5] = (__bf16)(f1.y * scale);
                bq0[ks][6] = (__bf16)(f1.z * scale); bq0[ks][7] = (__bf16)(f1.w * scale);
                float4 g0 = qpb[4 * ks + 2 * hl];
                float4 g1 = qpb[4 * ks + 2 * hl + 1];
                bq1[ks][0] = (__bf16)(g0.x * scale); bq1[ks][1] = (__bf16)(g0.y * scale);
                bq1[ks][2] = (__bf16)(g0.z * scale); bq1[ks][3] = (__bf16)(g0.w * scale);
                bq1[ks][4] = (__bf16)(g1.x * scale); bq1[ks][5] = (__bf16)(g1.y * scale);
                bq1[ks][6] = (__bf16)(g1.z * scale); bq1[ks][7] = (__bf16)(g1.w * scale);
            }
        }

        float mrun0 = (sidx == 0) ? sw : NEG_BIG;
        float mrun1 = mrun0;
        float lrun0 = (sidx == 0) ? 1.0f : 0.0f;
        float lrun1 = lrun0;
        f32x16 o00, o10, o01, o11;   // o[d-half][q-half]
        #pragma unroll
        for (int i = 0; i < 16; ++i) { o00[i] = 0.0f; o10[i] = 0.0f; o01[i] = 0.0f; o11[i] = 0.0f; }

        for (int j = j0; j < j1; ++j) {
            const int k0 = (ktA + j) * 64;

            __syncthreads();   // buf[par] staged & visible; prev reads done

            int nkt = -1;
            if (j + 1 < j1) nkt = ktA + j + 1;
            else if (s + 1 < ns) {
                const int it2 = SEG_IT[b24][s + 1];
                const int ktA2 = (2 * it2 - 16 > 0) ? (2 * it2 - 16) : 0;
                nkt = ktA2 + SEG_J0[b24][s + 1];
            }

            // ---- S^T = K · Q^T, both q-halves (K A-frags read ONCE) ----
            const __bf16* kb = k_lds[par];
            const __bf16* vb = v_lds[par];
            f32x16 s00, s10, s01, s11;   // s[key-half][q-half]
            #pragma unroll
            for (int i = 0; i < 16; ++i) { s00[i] = 0.0f; s10[i] = 0.0f; s01[i] = 0.0f; s11[i] = 0.0f; }
            __builtin_amdgcn_s_setprio(1);
            #pragma unroll
            for (int ks = 0; ks < 4; ++ks) {
                bf16x8 ka0 = *(const bf16x8*)&kb[swz(c,      2 * ks + hl)];
                bf16x8 ka1 = *(const bf16x8*)&kb[swz(32 + c, 2 * ks + hl)];
                s00 = __builtin_amdgcn_mfma_f32_32x32x16_bf16(ka0, bq0[ks], s00, 0, 0, 0);
                s10 = __builtin_amdgcn_mfma_f32_32x32x16_bf16(ka1, bq0[ks], s10, 0, 0, 0);
                s01 = __builtin_amdgcn_mfma_f32_32x32x16_bf16(ka0, bq1[ks], s01, 0, 0, 0);
                s11 = __builtin_amdgcn_mfma_f32_32x32x16_bf16(ka1, bq1[ks], s11, 0, 0, 0);
            }
            __builtin_amdgcn_s_setprio(0);

            // ---- mask (wave-uniform skip when interior for all 64 q) ----
            const bool interior = (k0 + 63 <= qw0) && (qw0 + 63 - k0 <= W);
            if (!interior) {
                mask_half(s00, s10, k0, qi0, W, hl);
                mask_half(s01, s11, k0, qi1, W, hl);
            }

            // ---- online softmax, exp2 domain, joint defer check ----
            float mx0 = xmax32(tree_max(s00, s10));
            float mx1 = xmax32(tree_max(s01, s11));
            if (!__all(fmaxf(mx0 - mrun0, mx1 - mrun1) <= 11.0f)) {
                const float mn0 = fmaxf(mrun0, mx0);
                const float al0 = exp2f(mrun0 - mn0);
                const float mn1 = fmaxf(mrun1, mx1);
                const float al1 = exp2f(mrun1 - mn1);
                lrun0 *= al0; lrun1 *= al1;
                #pragma unroll
                for (int i = 0; i < 16; ++i) {
                    o00[i] *= al0; o10[i] *= al0;
                    o01[i] *= al1; o11[i] *= al1;
                }
                mrun0 = mn0; mrun1 = mn1;
            }
            float ps0 = 0.0f, ps1 = 0.0f;
            #pragma unroll
            for (int i = 0; i < 16; ++i) {
                float p; 
                p = exp2f(s00[i] - mrun0); s00[i] = p; ps0 += p;
                p = exp2f(s10[i] - mrun0); s10[i] = p; ps0 += p;
                p = exp2f(s01[i] - mrun1); s01[i] = p; ps1 += p;
                p = exp2f(s11[i] - mrun1); s11[i] = p; ps1 += p;
            }
            lrun0 += xsum32(ps0);
            lrun1 += xsum32(ps1);

            // ---- exchange both halves (permlane, R16-proven) ----
            bf16x8 bp0[4], bp1[4];
            exch_bp(s00, s10, bp0);
            exch_bp(s01, s11, bp1);

            // ---- issue next tile's staging LOADS here (hidden under PV) ----
            if (nkt >= 0) {
                #pragma unroll
                for (int i = 0; i < 8; ++i) kreg[i] = kp4[nkt * 1024 + i * NT + t];
                #pragma unroll
                for (int kk = 0; kk < 8; ++kk) vreg[kk] = vp4[nkt * 1024 + (8 * kg + kk) * 16 + dgi];
            }

            // ---- O^T += V^T · P^T, both q-halves (V A-frags read ONCE) ----
            __builtin_amdgcn_s_setprio(1);
            #pragma unroll
            for (int ks = 0; ks < 4; ++ks) {
                bf16x8 va0 = *(const bf16x8*)&vb[swz(c,      2 * ks + hl)];
                bf16x8 va1 = *(const bf16x8*)&vb[swz(32 + c, 2 * ks + hl)];
                o00 = __builtin_amdgcn_mfma_f32_32x32x16_bf16(va0, bp0[ks], o00, 0, 0, 0);
                o10 = __builtin_amdgcn_mfma_f32_32x32x16_bf16(va1, bp0[ks], o10, 0, 0, 0);
                o01 = __builtin_amdgcn_mfma_f32_32x32x16_bf16(va0, bp1[ks], o01, 0, 0, 0);
                o11 = __builtin_amdgcn_mfma_f32_32x32x16_bf16(va1, bp1[ks], o11, 0, 0, 0);
            }
            __builtin_amdgcn_s_setprio(0);

            // ---- staging WRITES into the other buffer ----
            if (nkt >= 0) {
                const int np = par ^ 1;
                #pragma unroll
                for (int i = 0; i < 8; ++i) {
                    const int flat = i * NT + t;
                    const int key = flat >> 4, dd = flat & 15;
                    float4 f = kreg[i];
                    bf16x4 b = { (__bf16)f.x, (__bf16)f.y, (__bf16)f.z, (__bf16)f.w };
                    *(bf16x4*)&k_lds[np][swz(key, dd >> 1) + (dd & 1) * 4] = b;
                }
                bf16x4 p0, p1;
                p0 = bf16x4{ (__bf16)vreg[0].x, (__bf16)vreg[1].x, (__bf16)vreg[2].x, (__bf16)vreg[3].x };
                p1 = bf16x4{ (__bf16)vreg[4].x, (__bf16)vreg[5].x, (__bf16)vreg[6].x, (__bf16)vreg[7].x };
                *(bf16x4*)&v_lds[np][swz(4 * dgi + 0, kg) + 0] = p0;
                *(bf16x4*)&v_lds[np][swz(4 * dgi + 0, kg) + 4] = p1;
                p0 = bf16x4{ (__bf16)vreg[0].y, (__bf16)vreg[1].y, (__bf16)vreg[2].y, (__bf16)vreg[3].y };
                p1 = bf16x4{ (__bf16)vreg[4].y, (__bf16)vreg[5].y, (__bf16)vreg[6].y, (__bf16)vreg[7].y };
                *(bf16x4*)&v_lds[np][swz(4 * dgi + 1, kg) + 0] = p0;
                *(bf16x4*)&v_lds[np][swz(4 * dgi + 1, kg) + 4] = p1;
                p0 = bf16x4{ (__bf16)vreg[0].z, (__bf16)vreg[1].z, (__bf16)vreg[2].z, (__bf16)vreg[3].z };
                p1 = bf16x4{ (__bf16)vreg[4].z, (__bf16)vreg[5].z, (__bf16)vreg[6].z, (__bf16)vreg[7].z };
                *(bf16x4*)&v_lds[np][swz(4 * dgi + 2, kg) + 0] = p0;
                *(bf16x4*)&v_lds[np][swz(4 * dgi + 2, kg) + 4] = p1;
                p0 = bf16x4{ (__bf16)vreg[0].w, (__bf16)vreg[1].w, (__bf16)vreg[2].w, (__bf16)vreg[3].w };
                p1 = bf16x4{ (__bf16)vreg[4].w, (__bf16)vreg[5].w, (__bf16)vreg[6].w, (__bf16)vreg[7].w };
                *(bf16x4*)&v_lds[np][swz(4 * dgi + 3, kg) + 0] = p0;
                *(bf16x4*)&v_lds[np][swz(4 * dgi + 3, kg) + 4] = p1;
            }
            par ^= 1;
        }

        if (item < 2) {
            // ---- direct write, both halves ----
            const float inv0 = 1.0f / lrun0;
            const float inv1 = 1.0f / lrun1;
            float* ob0 = OUT + basebh + (size_t)qi0 * 64;
            float* ob1 = OUT + basebh + (size_t)qi1 * 64;
            #pragma unroll
            for (int rg = 0; rg < 4; ++rg) {
                float4 f0 = { o00[4*rg+0]*inv0, o00[4*rg+1]*inv0, o00[4*rg+2]*inv0, o00[4*rg+3]*inv0 };
                float4 f1 = { o10[4*rg+0]*inv0, o10[4*rg+1]*inv0, o10[4*rg+2]*inv0, o10[4*rg+3]*inv0 };
                *(float4*)&ob0[     8 * rg + 4 * hl] = f0;
                *(float4*)&ob0[32 + 8 * rg + 4 * hl] = f1;
                float4 g0 = { o01[4*rg+0]*inv1, o01[4*rg+1]*inv1, o01[4*rg+2]*inv1, o01[4*rg+3]*inv1 };
                float4 g1 = { o11[4*rg+0]*inv1, o11[4*rg+1]*inv1, o11[4*rg+2]*inv1, o11[4*rg+3]*inv1 };
                *(float4*)&ob1[     8 * rg + 4 * hl] = g0;
                *(float4*)&ob1[32 + 8 * rg + 4 * hl] = g1;
            }
        } else {
            // ---- write partials, both halves ----
            const int slot = (bh * 16 + item) * 3 + sidx;
            const int qr0 = 64 * w + c;
            const int qr1 = 64 * w + 32 + c;
            if (hl == 0) {
                ml_ws[(size_t)slot * 128 + qr0] = make_float2(mrun0, lrun0);
                ml_ws[(size_t)slot * 128 + qr1] = make_float2(mrun1, lrun1);
            }
            __bf16* Os0 = O_ws + (size_t)slot * 8192 + (size_t)qr0 * 64;
            __bf16* Os1 = O_ws + (size_t)slot * 8192 + (size_t)qr1 * 64;
            #pragma unroll
            for (int qd = 0; qd < 4; ++qd) {
                const int d0 = 8 * qd + 4 * hl;
                bf16x4 b0 = { (__bf16)o00[4*qd+0], (__bf16)o00[4*qd+1], (__bf16)o00[4*qd+2], (__bf16)o00[4*qd+3] };
                bf16x4 b1 = { (__bf16)o10[4*qd+0], (__bf16)o10[4*qd+1], (__bf16)o10[4*qd+2], (__bf16)o10[4*qd+3] };
                *(bf16x4*)&Os0[d0]      = b0;
                *(bf16x4*)&Os0[32 + d0] = b1;
                bf16x4 c0 = { (__bf16)o01[4*qd+0], (__bf16)o01[4*qd+1], (__bf16)o01[4*qd+2], (__bf16)o01[4*qd+3] };
                bf16x4 c1 = { (__bf16)o11[4*qd+0], (__bf16)o11[4*qd+1], (__bf16)o11[4*qd+2], (__bf16)o11[4*qd+3] };
                *(bf16x4*)&Os1[d0]      = c0;
                *(bf16x4*)&Os1[32 + d0] = c1;
            }
        }
    }
}

__global__ __launch_bounds__(256) void flex_r17_combine(
    const void* __restrict__ WS, float* __restrict__ OUT, const int H, const int S)
{
    const int NBH  = gridDim.x / 14;
    const int bi   = blockIdx.x;
    const int bh   = bi / 14;
    const int item = 2 + (bi - bh * 14);      // items 2..15 (multi-segment)
    const int ns   = NSEG_ITEM[item];
    const int t    = threadIdx.x;
    const int q    = t >> 1;
    const int half = t & 1;

    const __bf16* O_ws = (const __bf16*)WS;
    const float2* ml_ws = (const float2*)((const char*)WS + (size_t)NBH * 48 * 16384);
    const int base = (bh * 16 + item) * 3;

    float m[3], lv[3], a[3];
    float mst = NEG_BIG;
    for (int s = 0; s < ns; ++s) {
        float2 e = ml_ws[(size_t)(base + s) * 128 + q];
        m[s] = e.x; lv[s] = e.y;
        mst = fmaxf(mst, m[s]);
    }
    float lst = 0.0f;
    // m is in log2 domain (exp2 softmax) -> combine with exp2f
    for (int s = 0; s < ns; ++s) { a[s] = exp2f(m[s] - mst); lst += a[s] * lv[s]; }
    const float inv = 1.0f / lst;

    float acc[32];
    #pragma unroll
    for (int i = 0; i < 32; ++i) acc[i] = 0.0f;
    for (int s = 0; s < ns; ++s) {
        const __bf16* Os = O_ws + (size_t)(base + s) * 8192 + (size_t)q * 64 + 32 * half;
        const float as = a[s];
        #pragma unroll
        for (int v8 = 0; v8 < 4; ++v8) {
            bf16x8 o = *(const bf16x8*)&Os[8 * v8];
            #pragma unroll
            for (int jj = 0; jj < 8; ++jj) acc[8 * v8 + jj] += as * (float)o[jj];
        }
    }

    float* dst = OUT + (size_t)bh * S * 64 + (size_t)(item * 128 + q) * 64 + 32 * half;
    #pragma unroll
    for (int v4 = 0; v4 < 8; ++v4) {
        float4 f = { acc[4*v4+0] * inv, acc[4*v4+1] * inv,
                     acc[4*v4+2] * inv, acc[4*v4+3] * inv };
        *(float4*)&dst[4 * v4] = f;
    }
}

extern "C" void kernel_launch(void* const* d_in, const int* in_sizes, int n_in,
                              void* d_out, int out_size, void* d_ws, size_t ws_size,
                              hipStream_t stream) {
    const float* q     = (const float*)d_in[0];
    const float* k     = (const float*)d_in[1];
    const float* v     = (const float*)d_in[2];
    const float* sinkw = (const float*)d_in[3];
    const int*   swin  = (const int*)d_in[4];
    float* out = (float*)d_out;

    const int H = in_sizes[3];                   // 16
    const int S = 2048;
    const int B = in_sizes[0] / (H * S * 64);    // 2
    const int NBH = B * H;                       // 32

    flex_r17_main<<<dim3(NBH * 24), NT, 0, stream>>>(q, k, v, sinkw, swin, d_ws, out, H, S);
    flex_r17_combine<<<dim3(NBH * 14), 256, 0, stream>>>(d_ws, out, H, S);
}